// Round 6
// baseline (163.437 us; speedup 1.0000x reference)
//
#include <hip/hip_runtime.h>
#include <hip/hip_bf16.h>

// MobileMQA reduction (softmax over size-1 axis == 1; Q/K dead):
//   Wvt[d][c] = mean_h W_qkv[c][1024+h*64+d] (bf16), bv[d] likewise (f32)
//   V[b,n,d]  = sum_c x[b,c,n]*Wvt[d][c] + bv[d]     (gemm1, MFMA bf16, V stored bf16)
//   Z[b] = V[b] viewed (128,512); P[b] = Z[b]@Wproj + bproj   (gemm2, MFMA bf16)
//   out[b,c',i] = P[b, i&127, c']  fp32                (8x replication in gemm2 epilogue)
//
// R5: both GEMMs are LDS-free register-MFMA kernels (no staging barriers).
// Fragment mapping (verified by R4's passing kernel): A row / B col = lane&15,
// k = (lane>>4)*8 + j (8 consecutive k per lane = 16B). gemm1 A-frags come from
// 8 strided fp32 dword loads + v_cvt_pk; all other frags are single dwordx4.

typedef unsigned int u32;
typedef __attribute__((ext_vector_type(8))) short short8;  // 8 bf16 = 4 VGPR
typedef __attribute__((ext_vector_type(4))) float f32x4;

union FragU { u32 u[4]; short8 s; };

__device__ __forceinline__ u32 packbf2(float a, float b) {
  __hip_bfloat162 p = __float22bfloat162_rn(make_float2(a, b));
  return *(u32*)&p;
}

// blocks 0..255: Wproj 32x32 tile transpose -> Wpt bf16. blocks 256..383: Wvt + bv.
__global__ __launch_bounds__(256) void prep_kernel(
    const float* __restrict__ Wqkv, const float* __restrict__ bqkv,
    const float* __restrict__ Wproj, __hip_bfloat16* __restrict__ Wvt,
    float* __restrict__ bv, __hip_bfloat16* __restrict__ Wpt) {
  const int bid = blockIdx.x, t = (int)threadIdx.x;
  if (bid < 256) {
    __shared__ float Tl[32][33];
    const int tr = bid >> 4, tc = bid & 15;
    const int c0 = tr * 32, p0 = tc * 32;
    const int r = t >> 5, col = t & 31;
#pragma unroll
    for (int a = 0; a < 4; ++a)
      Tl[r + a * 8][col] = Wproj[(size_t)(c0 + r + a * 8) * 512 + p0 + col];
    __syncthreads();
#pragma unroll
    for (int a = 0; a < 4; ++a)
      Wpt[(size_t)(p0 + r + a * 8) * 512 + c0 + col] = __float2bfloat16(Tl[col][r + a * 8]);
  } else {
    const int g = (bid - 256) * 256 + t;  // 0..32767
    const int c = g >> 6, d = g & 63;
    float s = 0.f;
#pragma unroll
    for (int h = 0; h < 8; ++h) s += Wqkv[(size_t)c * 1536 + 1024 + h * 64 + d];
    Wvt[(size_t)d * 512 + c] = __float2bfloat16(s * 0.125f);
    if (g < 64) {
      float sb = 0.f;
#pragma unroll
      for (int h = 0; h < 8; ++h) sb += bqkv[1024 + h * 64 + d];
      bv[d] = sb * 0.125f;
    }
  }
}

// gemm1: grid (16 nt, 32 b), 256 thr = 4 waves (2x2 of 32n x 32d). LDS-free.
__global__ __launch_bounds__(256) void gemm1_kernel(
    const float* __restrict__ x, const __hip_bfloat16* __restrict__ Wvt,
    const float* __restrict__ bv, __hip_bfloat16* __restrict__ V) {
  const int nt = blockIdx.x, b = blockIdx.y;
  const int t = (int)threadIdx.x, w = t >> 6, lane = t & 63;
  const int wr = w >> 1, wc = w & 1;
  const int lr = lane & 15, ko = lane >> 4;
  // A source: x[b][c = kc + ko*8 + j][n = nt*64 + wr*32 + mi*16 + lr]
  const float* xg = x + (size_t)b * 524288 + (size_t)(ko * 8) * 1024 + nt * 64 + wr * 32 + lr;
  // B source: Wvt[d = wc*32 + ni*16 + lr][c = kc + ko*8 + 0..7]  (16B contiguous)
  const __hip_bfloat16* wg = Wvt + (size_t)(wc * 32 + lr) * 512 + ko * 8;

  float xv0[2][8], xv1[2][8];
  short8 br0[2], br1[2];
  f32x4 acc[2][2] = {{{0.f, 0.f, 0.f, 0.f}, {0.f, 0.f, 0.f, 0.f}},
                     {{0.f, 0.f, 0.f, 0.f}, {0.f, 0.f, 0.f, 0.f}}};

#define LX(dst, kc)                                                   \
  do {                                                                \
    _Pragma("unroll") for (int mi = 0; mi < 2; ++mi)                  \
    _Pragma("unroll") for (int j = 0; j < 8; ++j)                     \
        dst[mi][j] = xg[(size_t)((kc) + j) * 1024 + mi * 16];         \
  } while (0)
#define LB(dst, kc)                                                   \
  do {                                                                \
    _Pragma("unroll") for (int ni = 0; ni < 2; ++ni)                  \
        dst[ni] = *(const short8*)(wg + ni * 8192 + (kc));            \
  } while (0)
#define CMP1(xv, br)                                                  \
  do {                                                                \
    _Pragma("unroll") for (int mi = 0; mi < 2; ++mi) {                \
      FragU f;                                                        \
      _Pragma("unroll") for (int p = 0; p < 4; ++p)                   \
          f.u[p] = packbf2(xv[mi][2 * p], xv[mi][2 * p + 1]);         \
      _Pragma("unroll") for (int ni = 0; ni < 2; ++ni)                \
          acc[mi][ni] = __builtin_amdgcn_mfma_f32_16x16x32_bf16(      \
              f.s, br[ni], acc[mi][ni], 0, 0, 0);                     \
    }                                                                 \
  } while (0)

  LX(xv0, 0);  LB(br0, 0);
  LX(xv1, 32); LB(br1, 32);
  for (int kc = 0; kc < 512; kc += 64) {
    CMP1(xv0, br0);
    if (kc < 448) { LX(xv0, kc + 64); LB(br0, kc + 64); }
    CMP1(xv1, br1);
    if (kc < 448) { LX(xv1, kc + 96); LB(br1, kc + 96); }
  }
#undef LX
#undef LB
#undef CMP1

  // D: col (lane&15) = d-local, row = ko*4 + r = n-local. +bv, bf16 store.
#pragma unroll
  for (int ni = 0; ni < 2; ++ni) {
    const int d = wc * 32 + ni * 16 + lr;
    const float bvd = bv[d];
#pragma unroll
    for (int mi = 0; mi < 2; ++mi) {
      const int n0 = nt * 64 + wr * 32 + mi * 16 + ko * 4;
#pragma unroll
      for (int r = 0; r < 4; ++r)
        V[((size_t)b * 1024 + n0 + r) * 64 + d] = __float2bfloat16(acc[mi][ni][r] + bvd);
    }
  }
}

// gemm2: 512 blocks (XCD-chunked), 256 thr, tile 64j x 64c'. LDS-free main loop;
// LDS only for the epilogue P-transpose feeding 8x-replicated coalesced stores.
__global__ __launch_bounds__(256) void gemm2_kernel(
    const __hip_bfloat16* __restrict__ Vb, const __hip_bfloat16* __restrict__ Wpt,
    const float* __restrict__ bproj, float* __restrict__ out) {
  __shared__ float Pl[64 * 65];
  const int lin = (((int)blockIdx.x & 7) << 6) | ((int)blockIdx.x >> 3);  // XCD chunking
  const int ct = lin & 7, jt = (lin >> 3) & 1, b = lin >> 4;
  const int t = (int)threadIdx.x, w = t >> 6, lane = t & 63;
  const int wr = w >> 1, wc = w & 1;
  const int lr = lane & 15, ko = lane >> 4;
  // A: Z[j = jt*64 + wr*32 + mi*16 + lr][c = kc + ko*8 + 0..7] (Z = V[b] flat 128x512)
  const __hip_bfloat16* zg = Vb + (size_t)b * 65536 + (size_t)(jt * 64 + wr * 32 + lr) * 512 + ko * 8;
  // B: Wpt[p = ct*64 + wc*32 + ni*16 + lr][c = kc + ko*8 + 0..7]
  const __hip_bfloat16* wg = Wpt + (size_t)(ct * 64 + wc * 32 + lr) * 512 + ko * 8;

  short8 za0[2], za1[2], wb0[2], wb1[2];
  f32x4 acc[2][2] = {{{0.f, 0.f, 0.f, 0.f}, {0.f, 0.f, 0.f, 0.f}},
                     {{0.f, 0.f, 0.f, 0.f}, {0.f, 0.f, 0.f, 0.f}}};

#define LZ(dst, kc)                                                   \
  do {                                                                \
    _Pragma("unroll") for (int mi = 0; mi < 2; ++mi)                  \
        dst[mi] = *(const short8*)(zg + mi * 8192 + (kc));            \
  } while (0)
#define LW(dst, kc)                                                   \
  do {                                                                \
    _Pragma("unroll") for (int ni = 0; ni < 2; ++ni)                  \
        dst[ni] = *(const short8*)(wg + ni * 8192 + (kc));            \
  } while (0)
#define CMP2(za, wb)                                                  \
  do {                                                                \
    _Pragma("unroll") for (int mi = 0; mi < 2; ++mi)                  \
    _Pragma("unroll") for (int ni = 0; ni < 2; ++ni)                  \
        acc[mi][ni] = __builtin_amdgcn_mfma_f32_16x16x32_bf16(        \
            za[mi], wb[ni], acc[mi][ni], 0, 0, 0);                    \
  } while (0)

  LZ(za0, 0);  LW(wb0, 0);
  LZ(za1, 32); LW(wb1, 32);
  for (int kc = 0; kc < 512; kc += 64) {
    CMP2(za0, wb0);
    if (kc < 448) { LZ(za0, kc + 64); LW(wb0, kc + 64); }
    CMP2(za1, wb1);
    if (kc < 448) { LZ(za1, kc + 96); LW(wb1, kc + 96); }
  }
#undef LZ
#undef LW
#undef CMP2

  // P tile (+bproj) -> LDS [64][65] f32
#pragma unroll
  for (int ni = 0; ni < 2; ++ni) {
    const int p = wc * 32 + ni * 16 + lr;
    const float bp = bproj[ct * 64 + p];
#pragma unroll
    for (int mi = 0; mi < 2; ++mi) {
      const int j0 = wr * 32 + mi * 16 + ko * 4;
#pragma unroll
      for (int r = 0; r < 4; ++r) Pl[(j0 + r) * 65 + p] = acc[mi][ni][r] + bp;
    }
  }
  __syncthreads();
  // out[b][ct*64+cl][rep*128 + jt*64 + j] ; 8192 float4 per block, fully coalesced
  float* ob = out + ((size_t)b * 512 + ct * 64) * 1024 + jt * 64;
#pragma unroll 8
  for (int k = 0; k < 32; ++k) {
    int F = t + 256 * k;
    int cl = F >> 7;
    int rem = F & 127;
    int rep = rem >> 4;
    int j4 = (rem & 15) * 4;
    float4 v;
    v.x = Pl[(j4 + 0) * 65 + cl];
    v.y = Pl[(j4 + 1) * 65 + cl];
    v.z = Pl[(j4 + 2) * 65 + cl];
    v.w = Pl[(j4 + 3) * 65 + cl];
    *(float4*)(ob + (size_t)cl * 1024 + rep * 128 + j4) = v;
  }
}

extern "C" void kernel_launch(void* const* d_in, const int* in_sizes, int n_in,
                              void* d_out, int out_size, void* d_ws, size_t ws_size,
                              hipStream_t stream) {
  (void)in_sizes; (void)n_in; (void)out_size; (void)ws_size;
  const float* x     = (const float*)d_in[0];
  const float* Wqkv  = (const float*)d_in[1];
  const float* bqkv  = (const float*)d_in[2];
  const float* Wproj = (const float*)d_in[3];
  const float* bproj = (const float*)d_in[4];
  float* out = (float*)d_out;
  char* ws = (char*)d_ws;
  __hip_bfloat16* Wvt = (__hip_bfloat16*)(ws);            // 64*512*2   = 65536 B
  __hip_bfloat16* Wpt = (__hip_bfloat16*)(ws + 65536);    // 512*512*2  = 524288 B
  float*          bv  = (float*)(ws + 589824);            // 256 B
  __hip_bfloat16* Vb  = (__hip_bfloat16*)(ws + 590080);   // 32*1024*64*2 = 4 MiB

  prep_kernel<<<384, 256, 0, stream>>>(Wqkv, bqkv, Wproj, Wvt, bv, Wpt);
  gemm1_kernel<<<dim3(16, 32), 256, 0, stream>>>(x, Wvt, bv, Vb);
  gemm2_kernel<<<512, 256, 0, stream>>>(Vb, Wpt, bproj, out);
}

// Round 7
// 133.081 us; speedup vs baseline: 1.2281x; 1.2281x over previous
//
#include <hip/hip_runtime.h>
#include <hip/hip_bf16.h>

// MobileMQA reduction (softmax over size-1 axis == 1; Q/K dead):
//   Wvt[d][c] = mean_h W_qkv[c][1024+h*64+d] (bf16), bv[d] likewise (f32)
//   V[b,n,d]  = sum_c x[b,c,n]*Wvt[d][c] + bv[d]     (gemm1, MFMA bf16, V stored bf16)
//   Z[b] = V[b] viewed (128,512); P[b] = Z[b]@Wproj + bproj   (gemm2, MFMA bf16)
//   out[b,c',i] = P[b, i&127, c']  fp32                (8x replication in gemm2 epilogue)
//
// R7: back to R4's LDS+global_load_lds pipeline (R6 LDS-free regressed), with
// occupancy doubled: 32-row tiles -> 1024 blocks per GEMM (4 blocks/CU, 16
// waves/CU vs R4's 2/8). LDS 24KB/block. Swizzle: byte ^= ((row&7)<<4) both
// sides (write/pre-swizzled-source AND read).

typedef unsigned int u32;
typedef __attribute__((ext_vector_type(8))) short short8;  // 8 bf16 = 4 VGPR
typedef __attribute__((ext_vector_type(4))) float f32x4;

__device__ __forceinline__ void gll16(const void* g, void* l) {
  __builtin_amdgcn_global_load_lds(
      (const __attribute__((address_space(1))) u32*)g,
      (__attribute__((address_space(3))) u32*)l, 16, 0, 0);
}
__device__ __forceinline__ u32 packbf2(float a, float b) {
  __hip_bfloat162 p = __float22bfloat162_rn(make_float2(a, b));
  return *(u32*)&p;
}

// blocks 0..255: Wproj 32x32 tile transpose -> Wpt bf16. blocks 256..383: Wvt + bv.
__global__ __launch_bounds__(256) void prep_kernel(
    const float* __restrict__ Wqkv, const float* __restrict__ bqkv,
    const float* __restrict__ Wproj, __hip_bfloat16* __restrict__ Wvt,
    float* __restrict__ bv, __hip_bfloat16* __restrict__ Wpt) {
  const int bid = blockIdx.x, t = (int)threadIdx.x;
  if (bid < 256) {
    __shared__ float Tl[32][33];
    const int tr = bid >> 4, tc = bid & 15;
    const int c0 = tr * 32, p0 = tc * 32;
    const int r = t >> 5, col = t & 31;
#pragma unroll
    for (int a = 0; a < 4; ++a)
      Tl[r + a * 8][col] = Wproj[(size_t)(c0 + r + a * 8) * 512 + p0 + col];
    __syncthreads();
#pragma unroll
    for (int a = 0; a < 4; ++a)
      Wpt[(size_t)(p0 + r + a * 8) * 512 + c0 + col] = __float2bfloat16(Tl[col][r + a * 8]);
  } else {
    const int g = (bid - 256) * 256 + t;  // 0..32767
    const int c = g >> 6, d = g & 63;
    float s = 0.f;
#pragma unroll
    for (int h = 0; h < 8; ++h) s += Wqkv[(size_t)c * 1536 + 1024 + h * 64 + d];
    Wvt[(size_t)d * 512 + c] = __float2bfloat16(s * 0.125f);
    if (g < 64) {
      float sb = 0.f;
#pragma unroll
      for (int h = 0; h < 8; ++h) sb += bqkv[1024 + h * 64 + d];
      bv[d] = sb * 0.125f;
    }
  }
}

// gemm1: grid (32 nt, 32 b), 256 thr = 4 waves (wave w = d-quarter, 32n x 16d each).
// Block tile 32n x 64d, BK=64, double-buffered. X: fp32 float4 loads -> bf16
// pack -> swizzled LDS [n][c]. Wvt: global_load_lds w=16, pre-swizzled source.
__global__ __launch_bounds__(256) void gemm1_kernel(
    const float* __restrict__ x, const __hip_bfloat16* __restrict__ Wvt,
    const float* __restrict__ bv, __hip_bfloat16* __restrict__ V) {
  __shared__ char smem[24576];  // Xl[2][4096] | Wl[2][8192] at +8192
  char* Xl0 = smem;
  char* Wl0 = smem + 8192;
  const int nt = blockIdx.x, b = blockIdx.y;
  const int t = (int)threadIdx.x, w = t >> 6, lane = t & 63;
  const int lr = lane & 15, ko = lane >> 4;
  const int cq = t >> 3, nq = t & 7;  // staging: c-pair base cq*2, n-quad nq
  const float* xg = x + (size_t)b * 524288 + (size_t)(cq * 2) * 1024 + nt * 32 + nq * 4;

  float4 xr0, xr1;
  f32x4 acc[2] = {{0.f, 0.f, 0.f, 0.f}, {0.f, 0.f, 0.f, 0.f}};

#define XLOAD(kc)                                                      \
  do {                                                                 \
    xr0 = *(const float4*)(xg + (size_t)(kc) * 65536);                 \
    xr1 = *(const float4*)(xg + (size_t)(kc) * 65536 + 1024);          \
  } while (0)
#define XWRITE(buf)                                                    \
  do {                                                                 \
    _Pragma("unroll") for (int j = 0; j < 4; ++j) {                    \
      int n = nq * 4 + j;                                              \
      u32 pv = packbf2(((const float*)&xr0)[j], ((const float*)&xr1)[j]); \
      *(u32*)(Xl0 + (buf) * 4096 + ((n * 128 + cq * 4) ^ ((n & 7) << 4))) = pv; \
    }                                                                  \
  } while (0)
#define WSTAGE(buf, kc)                                                \
  do {                                                                 \
    _Pragma("unroll") for (int q = 0; q < 2; ++q) {                    \
      int g = t + 256 * q;                                             \
      int r = g >> 3, ww = g & 7;                                      \
      gll16(Wvt + (size_t)r * 512 + (kc) * 64 + ((ww ^ (r & 7)) << 3), \
            Wl0 + (buf) * 8192 + g * 16);                              \
    }                                                                  \
  } while (0)

  XLOAD(0);
  WSTAGE(0, 0);
  XWRITE(0);
  __syncthreads();
  for (int kc = 0; kc < 8; ++kc) {
    const int cur = kc & 1;
    if (kc < 7) {
      XLOAD(kc + 1);
      WSTAGE(cur ^ 1, kc + 1);
    }
    const char* Xb = Xl0 + cur * 4096;
    const char* Wb = Wl0 + cur * 8192;
#pragma unroll
    for (int kb = 0; kb < 2; ++kb) {
      short8 af[2], bfr;
#pragma unroll
      for (int mi = 0; mi < 2; ++mi) {
        int n = mi * 16 + lr;
        af[mi] = *(const short8*)(Xb + ((n * 128 + kb * 64 + ko * 16) ^ ((n & 7) << 4)));
      }
      {
        int d = w * 16 + lr;
        bfr = *(const short8*)(Wb + d * 128 + (((kb * 4 + ko) ^ (d & 7)) << 4));
      }
#pragma unroll
      for (int mi = 0; mi < 2; ++mi)
        acc[mi] = __builtin_amdgcn_mfma_f32_16x16x32_bf16(af[mi], bfr, acc[mi], 0, 0, 0);
    }
    if (kc < 7) XWRITE(cur ^ 1);
    __syncthreads();
  }
#undef XLOAD
#undef XWRITE
#undef WSTAGE

  // D: col (lane&15) = d-local, row = ko*4 + r = n-local. +bv, bf16 store.
  const int d = w * 16 + lr;
  const float bvd = bv[d];
#pragma unroll
  for (int mi = 0; mi < 2; ++mi) {
    const int n0 = nt * 32 + mi * 16 + ko * 4;
#pragma unroll
    for (int r = 0; r < 4; ++r)
      V[((size_t)b * 1024 + n0 + r) * 64 + d] = __float2bfloat16(acc[mi][r] + bvd);
  }
}

// gemm2: 1024 blocks (XCD-chunked, bijective since 1024%8==0), 256 thr.
// Block tile 32j x 64c', BK=64, double-buffered; Z and Wpt both via
// global_load_lds with pre-swizzled source. Epilogue: P -> stride-65 LDS ->
// 8x-replicated coalesced float4 stores.
__global__ __launch_bounds__(256) void gemm2_kernel(
    const __hip_bfloat16* __restrict__ Vb, const __hip_bfloat16* __restrict__ Wpt,
    const float* __restrict__ bproj, float* __restrict__ out) {
  __shared__ char smem[24576];  // Zl[2][4096] | Wl[2][8192] at +8192; Pl aliases base
  char* Zl0 = smem;
  char* Wl0 = smem + 8192;
  const int bid = (int)blockIdx.x;
  const int lin = ((bid & 7) << 7) | (bid >> 3);  // XCD chunking
  const int ct = lin & 7, jt = (lin >> 3) & 3, b = lin >> 5;
  const int t = (int)threadIdx.x, w = t >> 6, lane = t & 63;
  const int lr = lane & 15, ko = lane >> 4;
  const __hip_bfloat16* Zg = Vb + (size_t)b * 65536 + (size_t)(jt * 32) * 512;
  const __hip_bfloat16* Wg = Wpt + (size_t)(ct * 64) * 512;

#define STAGE(buf, kc)                                                 \
  do {                                                                 \
    {                                                                  \
      int g = t;                                                       \
      int r = g >> 3, ww = g & 7;                                      \
      gll16(Zg + (size_t)r * 512 + (kc) * 64 + ((ww ^ (r & 7)) << 3),  \
            Zl0 + (buf) * 4096 + g * 16);                              \
    }                                                                  \
    _Pragma("unroll") for (int q = 0; q < 2; ++q) {                    \
      int g = t + 256 * q;                                             \
      int r = g >> 3, ww = g & 7;                                      \
      gll16(Wg + (size_t)r * 512 + (kc) * 64 + ((ww ^ (r & 7)) << 3),  \
            Wl0 + (buf) * 8192 + g * 16);                              \
    }                                                                  \
  } while (0)

  f32x4 acc[2] = {{0.f, 0.f, 0.f, 0.f}, {0.f, 0.f, 0.f, 0.f}};
  STAGE(0, 0);
  __syncthreads();
  for (int kc = 0; kc < 8; ++kc) {
    const int cur = kc & 1;
    if (kc < 7) STAGE(cur ^ 1, kc + 1);
    const char* Zb = Zl0 + cur * 4096;
    const char* Wb = Wl0 + cur * 8192;
#pragma unroll
    for (int kb = 0; kb < 2; ++kb) {
      short8 af[2], bfr;
#pragma unroll
      for (int mi = 0; mi < 2; ++mi) {
        int j = mi * 16 + lr;
        af[mi] = *(const short8*)(Zb + j * 128 + (((kb * 4 + ko) ^ (j & 7)) << 4));
      }
      {
        int p = w * 16 + lr;
        bfr = *(const short8*)(Wb + p * 128 + (((kb * 4 + ko) ^ (p & 7)) << 4));
      }
#pragma unroll
      for (int mi = 0; mi < 2; ++mi)
        acc[mi] = __builtin_amdgcn_mfma_f32_16x16x32_bf16(af[mi], bfr, acc[mi], 0, 0, 0);
    }
    __syncthreads();
  }
#undef STAGE

  // P tile (+bproj) -> LDS [32][65] f32 (aliases Zl; safe after final barrier)
  float* Pl = (float*)smem;
  const int p = w * 16 + lr;
  const float bp = bproj[ct * 64 + p];
#pragma unroll
  for (int mi = 0; mi < 2; ++mi) {
#pragma unroll
    for (int r = 0; r < 4; ++r)
      Pl[(mi * 16 + ko * 4 + r) * 65 + p] = acc[mi][r] + bp;
  }
  __syncthreads();
  // out[b][ct*64+cl][rep*128 + jt*32 + j]; 4096 float4 per block, coalesced
  float* ob = out + ((size_t)b * 512 + ct * 64) * 1024 + jt * 32;
#pragma unroll
  for (int k = 0; k < 16; ++k) {
    int F = t + 256 * k;
    int cl = F >> 6;       // 0..63
    int rem = F & 63;
    int rep = rem >> 3;    // 0..7
    int j4 = (rem & 7) * 4;  // 0..28
    float4 v;
    v.x = Pl[(j4 + 0) * 65 + cl];
    v.y = Pl[(j4 + 1) * 65 + cl];
    v.z = Pl[(j4 + 2) * 65 + cl];
    v.w = Pl[(j4 + 3) * 65 + cl];
    *(float4*)(ob + (size_t)cl * 1024 + rep * 128 + j4) = v;
  }
}

extern "C" void kernel_launch(void* const* d_in, const int* in_sizes, int n_in,
                              void* d_out, int out_size, void* d_ws, size_t ws_size,
                              hipStream_t stream) {
  (void)in_sizes; (void)n_in; (void)out_size; (void)ws_size;
  const float* x     = (const float*)d_in[0];
  const float* Wqkv  = (const float*)d_in[1];
  const float* bqkv  = (const float*)d_in[2];
  const float* Wproj = (const float*)d_in[3];
  const float* bproj = (const float*)d_in[4];
  float* out = (float*)d_out;
  char* ws = (char*)d_ws;
  __hip_bfloat16* Wvt = (__hip_bfloat16*)(ws);            // 64*512*2   = 65536 B
  __hip_bfloat16* Wpt = (__hip_bfloat16*)(ws + 65536);    // 512*512*2  = 524288 B
  float*          bv  = (float*)(ws + 589824);            // 256 B
  __hip_bfloat16* Vb  = (__hip_bfloat16*)(ws + 590080);   // 32*1024*64*2 = 4 MiB

  prep_kernel<<<384, 256, 0, stream>>>(Wqkv, bqkv, Wproj, Wvt, bv, Wpt);
  gemm1_kernel<<<dim3(32, 32), 256, 0, stream>>>(x, Wvt, bv, Vb);
  gemm2_kernel<<<1024, 256, 0, stream>>>(Vb, Wpt, bproj, out);
}